// Round 2
// baseline (948.926 us; speedup 1.0000x reference)
//
#include <hip/hip_runtime.h>

// Problem constants
#define Bx    2
#define Sx    2048
#define Dx    1024
#define Hx    16
#define DEPTHx 64
#define NCx   (Sx/64)     // 32 chunks per sequence
#define BHx   (Bx*Hx)     // 32
#define Mx    (Bx*Sx)     // 4096

// ---------------------------------------------------------------------------
// GEMM: C[M,N] = act( (A .* mask) @ W + bias ), M=4096, N=K=1024, fp32 VALU
// 128x128 tile, BK=16, 256 threads, 8x8 per thread in 2x2 quadrants.
// ---------------------------------------------------------------------------
#define BM 128
#define BN 128
#define BK 16

__global__ __launch_bounds__(256, 2) void gemm_kernel(
    const float* __restrict__ A, const float* __restrict__ W,
    const float* __restrict__ bias, const float* __restrict__ mask,
    float* __restrict__ C, int leaky)
{
  const int Kd = 1024, Nd = 1024;
  __shared__ float As[BK][BM + 4];   // [k][m], pad 4 -> stride 132 (16B aligned rows)
  __shared__ float Bs[BK][BN + 4];   // [k][n]
  const int tid = threadIdx.x;
  const int m0 = blockIdx.y * BM;
  const int n0 = blockIdx.x * BN;
  const int tm = tid / 16;           // 0..15 row group
  const int tn = tid % 16;           // 0..15 col group
  const int arow = tid >> 2;         // 0..63
  const int akq  = tid & 3;          // k-quad for A loads
  const int brow = tid >> 5;         // 0..7
  const int bnq  = tid & 31;         // n-quad for B loads

  float mf0 = 1.f, mf1 = 1.f;
  if (mask) { mf0 = mask[m0 + arow]; mf1 = mask[m0 + arow + 64]; }

  const float* Ap = A + (size_t)(m0 + arow) * Kd + (akq << 2);
  const float* Bp = W + (size_t)brow * Nd + n0 + (bnq << 2);

  float acc[8][8];
#pragma unroll
  for (int i = 0; i < 8; i++)
#pragma unroll
    for (int j = 0; j < 8; j++) acc[i][j] = 0.f;

  for (int kt = 0; kt < Kd; kt += BK) {
    float4 a0 = *(const float4*)(Ap + kt);
    float4 a1 = *(const float4*)(Ap + (size_t)64 * Kd + kt);
    float4 b0 = *(const float4*)(Bp + (size_t)kt * Nd);
    float4 b1 = *(const float4*)(Bp + (size_t)(kt + 8) * Nd);
    a0.x *= mf0; a0.y *= mf0; a0.z *= mf0; a0.w *= mf0;
    a1.x *= mf1; a1.y *= mf1; a1.z *= mf1; a1.w *= mf1;
    __syncthreads();
    As[(akq << 2) + 0][arow]      = a0.x;
    As[(akq << 2) + 1][arow]      = a0.y;
    As[(akq << 2) + 2][arow]      = a0.z;
    As[(akq << 2) + 3][arow]      = a0.w;
    As[(akq << 2) + 0][arow + 64] = a1.x;
    As[(akq << 2) + 1][arow + 64] = a1.y;
    As[(akq << 2) + 2][arow + 64] = a1.z;
    As[(akq << 2) + 3][arow + 64] = a1.w;
    *(float4*)&Bs[brow][bnq << 2]     = b0;
    *(float4*)&Bs[brow + 8][bnq << 2] = b1;
    __syncthreads();
#pragma unroll
    for (int kk = 0; kk < BK; kk++) {
      float4 xa0 = *(float4*)&As[kk][tm << 2];
      float4 xa1 = *(float4*)&As[kk][64 + (tm << 2)];
      float4 xb0 = *(float4*)&Bs[kk][tn << 2];
      float4 xb1 = *(float4*)&Bs[kk][64 + (tn << 2)];
      float av[8] = {xa0.x, xa0.y, xa0.z, xa0.w, xa1.x, xa1.y, xa1.z, xa1.w};
      float bv[8] = {xb0.x, xb0.y, xb0.z, xb0.w, xb1.x, xb1.y, xb1.z, xb1.w};
#pragma unroll
      for (int i = 0; i < 8; i++)
#pragma unroll
        for (int j = 0; j < 8; j++) acc[i][j] += av[i] * bv[j];
    }
  }

#pragma unroll
  for (int ih = 0; ih < 2; ih++)
#pragma unroll
    for (int i = 0; i < 4; i++) {
      const int m = m0 + ih * 64 + (tm << 2) + i;
      const int r = ih * 4 + i;
#pragma unroll
      for (int jh = 0; jh < 2; jh++) {
        const int n = n0 + jh * 64 + (tn << 2);
        float4 o;
        o.x = acc[r][jh * 4 + 0] + bias[n + 0];
        o.y = acc[r][jh * 4 + 1] + bias[n + 1];
        o.z = acc[r][jh * 4 + 2] + bias[n + 2];
        o.w = acc[r][jh * 4 + 3] + bias[n + 3];
        if (leaky) {
          o.x = o.x >= 0.f ? o.x : 0.1f * o.x;
          o.y = o.y >= 0.f ? o.y : 0.1f * o.y;
          o.z = o.z >= 0.f ? o.z : 0.1f * o.z;
          o.w = o.w >= 0.f ? o.w : 0.1f * o.w;
        }
        *(float4*)&C[(size_t)m * Nd + n] = o;
      }
    }
}

// ---------------------------------------------------------------------------
// Phase 1: per-chunk KV = K_c^T V_c  (stored transposed: ckv[e*64+d] = KV[d][e])
//          and per-chunk k-sum. One block per (b,h,chunk).
// ---------------------------------------------------------------------------
__global__ __launch_bounds__(256) void chunkkv_kernel(
    const float* __restrict__ kp, const float* __restrict__ vp,
    float* __restrict__ ckv, float* __restrict__ cz)
{
  __shared__ float Ks[64][68];
  __shared__ float Vs[64][68];
  const int blk = blockIdx.x;
  const int c = blk & (NCx - 1);
  const int bh = blk / NCx;
  const int b = bh / Hx, h = bh % Hx;
  const int tid = threadIdx.x;
  const size_t rowbase = ((size_t)(b * Sx + c * 64)) * Dx + h * 64;
#pragma unroll
  for (int j = 0; j < 4; j++) {
    int f = tid + 256 * j;
    int t = f >> 4, dq = f & 15;
    *(float4*)&Ks[t][dq << 2] = *(const float4*)&kp[rowbase + (size_t)t * Dx + (dq << 2)];
    *(float4*)&Vs[t][dq << 2] = *(const float4*)&vp[rowbase + (size_t)t * Dx + (dq << 2)];
  }
  __syncthreads();
  const int d = tid & 63;
  const int eg = tid >> 6;
  float acc[16];
#pragma unroll
  for (int i = 0; i < 16; i++) acc[i] = 0.f;
  float sk = 0.f;
  for (int t = 0; t < 64; t++) {
    float kv = Ks[t][d];
    sk += kv;
#pragma unroll
    for (int i = 0; i < 16; i++) acc[i] += kv * Vs[t][eg * 16 + i];
  }
  const size_t ob = (size_t)blk * 4096;
#pragma unroll
  for (int i = 0; i < 16; i++) ckv[ob + (size_t)(eg * 16 + i) * 64 + d] = acc[i];
  if (eg == 0) cz[(size_t)blk * 64 + d] = sk;
}

// ---------------------------------------------------------------------------
// Phase 2: in-place exclusive prefix over chunks per (b,h). One block per bh.
// ---------------------------------------------------------------------------
__global__ __launch_bounds__(256) void prefix_kernel(
    float* __restrict__ ckv, float* __restrict__ cz)
{
  const int bh = blockIdx.x;
  const int tid = threadIdx.x;
  float acc[16];
#pragma unroll
  for (int j = 0; j < 16; j++) acc[j] = 0.f;
  float az = 0.f;
  for (int c = 0; c < NCx; c++) {
    const size_t base = ((size_t)(bh * NCx + c)) * 4096;
#pragma unroll
    for (int j = 0; j < 16; j++) {
      float v = ckv[base + tid + 256 * j];
      ckv[base + tid + 256 * j] = acc[j];
      acc[j] += v;
    }
    if (tid < 64) {
      const size_t zb = (size_t)(bh * NCx + c) * 64 + tid;
      float v = cz[zb]; cz[zb] = az; az += v;
    }
  }
}

// ---------------------------------------------------------------------------
// Phase 3: per-chunk output.
//   out_t[e] = ( q_t . Sexcl[:,e] + sum_{s<=t} (q_t.k_s) v_s[e] )
//            / ( q_t . z_excl + sum_{s<=t} q_t.k_s )
// One block per (b,h,chunk); thread = (t = tid/4, sg = tid%4 -> e-block sg*16..+15).
// LDS = Qs+Ks+As+small = 53.5 KB -> 3 blocks/CU. V and Sexcl read from global
// (16 KB each per block, L1-resident broadcast reads).
// Writes land in [B,S,D] "concat" layout directly.
// ---------------------------------------------------------------------------
__global__ __launch_bounds__(256) void attn_kernel(
    const float* __restrict__ qp, const float* __restrict__ kp,
    const float* __restrict__ vp, const float* __restrict__ ckv,
    const float* __restrict__ cz, float* __restrict__ concat)
{
  __shared__ float Qs[64][68];
  __shared__ float Ks[64][68];
  __shared__ float As[64][68];
  __shared__ float zs[64];
  __shared__ float den4[64][4];
  const int blk = blockIdx.x;
  const int c = blk & (NCx - 1);
  const int bh = blk / NCx;
  const int b = bh / Hx, h = bh % Hx;
  const int tid = threadIdx.x;
  const size_t rowbase = ((size_t)(b * Sx + c * 64)) * Dx + h * 64;
#pragma unroll
  for (int j = 0; j < 4; j++) {
    int f = tid + 256 * j;
    int t = f >> 4, dq = f & 15;
    *(float4*)&Qs[t][dq << 2] = *(const float4*)&qp[rowbase + (size_t)t * Dx + (dq << 2)];
    *(float4*)&Ks[t][dq << 2] = *(const float4*)&kp[rowbase + (size_t)t * Dx + (dq << 2)];
  }
  if (tid < 64) zs[tid] = cz[(size_t)blk * 64 + tid];
  __syncthreads();

  const int t = tid >> 2;
  const int sg = tid & 3;

  // A = tril(Q K^T), row t computed by 4 threads (s = sg + 4*si)
  float dp = 0.f;
#pragma unroll
  for (int si = 0; si < 16; si++) {
    const int s = sg + (si << 2);
    float a = 0.f;
    if (s <= t) {
#pragma unroll
      for (int d = 0; d < 64; d += 4) {
        float4 qv = *(float4*)&Qs[t][d];
        float4 kv = *(float4*)&Ks[s][d];
        a += qv.x * kv.x + qv.y * kv.y + qv.z * kv.z + qv.w * kv.w;
      }
      dp += a;
    }
    As[t][s] = a;
  }
  // q . z_excl partial (this thread's d-quarter)
#pragma unroll
  for (int d = sg * 16; d < sg * 16 + 16; d += 4) {
    float4 qv = *(float4*)&Qs[t][d];
    float4 zv = *(float4*)&zs[d];
    dp += qv.x * zv.x + qv.y * zv.y + qv.z * zv.z + qv.w * zv.w;
  }
  den4[t][sg] = dp;
  __syncthreads();
  const float den = den4[t][0] + den4[t][1] + den4[t][2] + den4[t][3];

  float num[16];
#pragma unroll
  for (int i = 0; i < 16; i++) num[i] = 0.f;

  // Q @ S_excl  (ckv global layout [e][d], this block's 16KB slab, L1-resident)
  const size_t stb = (size_t)blk * 4096;
#pragma unroll
  for (int i = 0; i < 16; i++) {
    const int e = sg * 16 + i;
    float a0 = 0.f;
#pragma unroll
    for (int d = 0; d < 64; d += 4) {
      float4 qv = *(float4*)&Qs[t][d];
      float4 sv = *(const float4*)&ckv[stb + (size_t)e * 64 + d];
      a0 += qv.x * sv.x + qv.y * sv.y + qv.z * sv.z + qv.w * sv.w;
    }
    num[i] = a0;
  }

  // tril(A) @ V  (V rows from global, f4 over e; L1-resident 16KB chunk)
  const size_t vbase = ((size_t)(b * Sx + c * 64)) * Dx + h * 64 + sg * 16;
  for (int s = 0; s <= t; s++) {
    const float av = As[t][s];
    const float* vrow = &vp[vbase + (size_t)s * Dx];
#pragma unroll
    for (int ii = 0; ii < 4; ii++) {
      float4 vv = *(const float4*)(vrow + ii * 4);
      num[ii * 4 + 0] += av * vv.x;
      num[ii * 4 + 1] += av * vv.y;
      num[ii * 4 + 2] += av * vv.z;
      num[ii * 4 + 3] += av * vv.w;
    }
  }

  const float inv = 1.f / den;
  float* orow = &concat[((size_t)(b * Sx + c * 64 + t)) * Dx + h * 64 + sg * 16];
#pragma unroll
  for (int ii = 0; ii < 4; ii++) {
    float4 o;
    o.x = num[ii * 4 + 0] * inv;
    o.y = num[ii * 4 + 1] * inv;
    o.z = num[ii * 4 + 2] * inv;
    o.w = num[ii * 4 + 3] * inv;
    *(float4*)(orow + ii * 4) = o;
  }
}

// ---------------------------------------------------------------------------
extern "C" void kernel_launch(void* const* d_in, const int* in_sizes, int n_in,
                              void* d_out, int out_size, void* d_ws, size_t ws_size,
                              hipStream_t stream)
{
  const float* q  = (const float*)d_in[0];
  const float* k  = (const float*)d_in[1];
  const float* v  = (const float*)d_in[2];
  const float* qm = (const float*)d_in[3];
  const float* km = (const float*)d_in[4];
  const float* vm = (const float*)d_in[5];
  const float* Wq = (const float*)d_in[6];
  const float* bq = (const float*)d_in[7];
  const float* Wk = (const float*)d_in[8];
  const float* bk = (const float*)d_in[9];
  const float* Wv = (const float*)d_in[10];
  const float* bv = (const float*)d_in[11];
  const float* Wo = (const float*)d_in[12];
  const float* bo = (const float*)d_in[13];
  float* out = (float*)d_out;

  // workspace layout (floats): qp, kp, vp, ckv (4,194,304 each), cz (65,536),
  // concat (4,194,304 if room; else safely aliases qp — phase3 block writes only
  // the exact region it already consumed into LDS).
  float* qp  = (float*)d_ws;
  float* kp  = qp + 4194304;
  float* vp  = kp + 4194304;
  float* ckv = vp + 4194304;
  float* cz  = ckv + 4194304;
  float* concat = (ws_size >= (size_t)84148224) ? (cz + 65536) : qp;

  dim3 ggrid(1024 / BN, Mx / BM);  // (8, 32)

  gemm_kernel<<<ggrid, 256, 0, stream>>>(q, Wq, bq, qm, qp, 1);
  gemm_kernel<<<ggrid, 256, 0, stream>>>(k, Wk, bk, km, kp, 1);
  gemm_kernel<<<ggrid, 256, 0, stream>>>(v, Wv, bv, vm, vp, 0);
  chunkkv_kernel<<<BHx * NCx, 256, 0, stream>>>(kp, vp, ckv, cz);
  prefix_kernel<<<BHx, 256, 0, stream>>>(ckv, cz);
  attn_kernel<<<BHx * NCx, 256, 0, stream>>>(qp, kp, vp, ckv, cz, concat);
  gemm_kernel<<<ggrid, 256, 0, stream>>>(concat, Wo, bo, nullptr, out, 0);
}

// Round 4
// 312.045 us; speedup vs baseline: 3.0410x; 3.0410x over previous
//
#include <hip/hip_runtime.h>

// Problem constants
#define Bx    2
#define Sx    2048
#define Dx    1024
#define Hx    16
#define NCx   (Sx/64)     // 32 chunks per sequence
#define BHx   (Bx*Hx)     // 32
#define Mx    (Bx*Sx)     // 4096

typedef float    f4 __attribute__((ext_vector_type(4)));
typedef _Float16 h8 __attribute__((ext_vector_type(8)));
typedef _Float16 h4 __attribute__((ext_vector_type(4)));

// ---------------------------------------------------------------------------
// convert_in: xh[i] = (fp16)(x[i] * mask[row])   (4096x1024)
// ---------------------------------------------------------------------------
__global__ __launch_bounds__(256) void convert_in(
    const float* __restrict__ x, const float* __restrict__ mask,
    _Float16* __restrict__ xh)
{
  const int i4 = blockIdx.x * 256 + threadIdx.x;   // 0..1048575
  const f4 v = *(const f4*)(x + (size_t)i4 * 4);
  const float mf = mask[i4 >> 8];
  h4 o;
  o[0] = (_Float16)(v[0] * mf);
  o[1] = (_Float16)(v[1] * mf);
  o[2] = (_Float16)(v[2] * mf);
  o[3] = (_Float16)(v[3] * mf);
  *(h4*)(xh + (size_t)i4 * 4) = o;
}

// ---------------------------------------------------------------------------
// convert_w: Wt[n][k] = (fp16) W[k][n]  for 4 weights (blockIdx.z selects).
// 64x64 tiles via LDS.
// ---------------------------------------------------------------------------
__global__ __launch_bounds__(256) void convert_w(
    const float* __restrict__ W0, const float* __restrict__ W1,
    const float* __restrict__ W2, const float* __restrict__ W3,
    _Float16* __restrict__ T0, _Float16* __restrict__ T1,
    _Float16* __restrict__ T2, _Float16* __restrict__ T3)
{
  const float* W = (blockIdx.z == 0) ? W0 : (blockIdx.z == 1) ? W1 :
                   (blockIdx.z == 2) ? W2 : W3;
  _Float16* T = (blockIdx.z == 0) ? T0 : (blockIdx.z == 1) ? T1 :
                (blockIdx.z == 2) ? T2 : T3;
  __shared__ float Ws[64 * 68];
  const int tx = threadIdx.x & 15, ty = threadIdx.x >> 4;
  const int k0 = blockIdx.y * 64, n0 = blockIdx.x * 64;
#pragma unroll
  for (int i = 0; i < 4; i++) {
    const int r = ty + 16 * i;
    *(f4*)&Ws[r * 68 + tx * 4] = *(const f4*)&W[(size_t)(k0 + r) * Dx + n0 + tx * 4];
  }
  __syncthreads();
#pragma unroll
  for (int i = 0; i < 4; i++) {
    const int n = ty + 16 * i;
    h4 o;
#pragma unroll
    for (int j = 0; j < 4; j++) o[j] = (_Float16)Ws[(tx * 4 + j) * 68 + n];
    *(h4*)&T[(size_t)(n0 + n) * Dx + k0 + tx * 4] = o;
  }
}

// ---------------------------------------------------------------------------
// gemm_f16: C[M,N] = act(A @ Bt^T + bias); A fp16 [M,1024], Bt fp16 [N=1024][K]
// MFMA 16x16x32_f16. 128x128 tile, 256 thr = 4 waves (2x2), 4x4 frags/wave.
// LDS rows padded to 40 halves -> frag b128 reads are 2-way (free).
// Staging: 128 rows x 32 halves = 4096 halves/buffer; 256 threads x 16 halves
// (thread = row tid>>1, half-row ck=tid&1 -> [ck*16, ck*16+16)).  [R3 bug:
// only halves 0..15 were staged -> uninitialized LDS -> NaN. Fixed.]
// ---------------------------------------------------------------------------
__global__ __launch_bounds__(256) void gemm_f16(
    const _Float16* __restrict__ A, const _Float16* __restrict__ Bt,
    const float* __restrict__ bias, void* __restrict__ Cout,
    int leaky, int half_out)
{
  __shared__ _Float16 As[128 * 40];
  __shared__ _Float16 Bs[128 * 40];
  const int tid = threadIdx.x;
  const int m0 = blockIdx.y * 128, n0 = blockIdx.x * 128;
  const int row = tid >> 1, ck = tid & 1;          // staging: 32B per thread/buffer
  const _Float16* ga = A  + (size_t)(m0 + row) * Dx + (ck << 4);
  const _Float16* gb = Bt + (size_t)(n0 + row) * Dx + (ck << 4);
  const int lane = tid & 63, wave = tid >> 6;
  const int wr = wave >> 1, wc = wave & 1;
  const int lm = lane & 15, qd = lane >> 4;

  f4 acc[4][4];
#pragma unroll
  for (int i = 0; i < 4; i++)
#pragma unroll
    for (int j = 0; j < 4; j++) { f4 z = {0.f, 0.f, 0.f, 0.f}; acc[i][j] = z; }

  for (int kt = 0; kt < Dx; kt += 32) {
    h8 va0 = *(const h8*)(ga + kt);
    h8 va1 = *(const h8*)(ga + kt + 8);
    h8 vb0 = *(const h8*)(gb + kt);
    h8 vb1 = *(const h8*)(gb + kt + 8);
    __syncthreads();
    *(h8*)&As[row * 40 + (ck << 4)]     = va0;
    *(h8*)&As[row * 40 + (ck << 4) + 8] = va1;
    *(h8*)&Bs[row * 40 + (ck << 4)]     = vb0;
    *(h8*)&Bs[row * 40 + (ck << 4) + 8] = vb1;
    __syncthreads();
    h8 af[4], bf[4];
#pragma unroll
    for (int i = 0; i < 4; i++)
      af[i] = *(const h8*)&As[(wr * 64 + i * 16 + lm) * 40 + qd * 8];
#pragma unroll
    for (int j = 0; j < 4; j++)
      bf[j] = *(const h8*)&Bs[(wc * 64 + j * 16 + lm) * 40 + qd * 8];
#pragma unroll
    for (int i = 0; i < 4; i++)
#pragma unroll
      for (int j = 0; j < 4; j++)
        acc[i][j] = __builtin_amdgcn_mfma_f32_16x16x32_f16(af[i], bf[j], acc[i][j], 0, 0, 0);
  }

  // epilogue: C/D layout col=lane&15, row=quad*4+reg  [verified m89/m120]
#pragma unroll
  for (int j = 0; j < 4; j++) {
    const int n = n0 + wc * 64 + j * 16 + lm;
    const float bz = bias[n];
#pragma unroll
    for (int i = 0; i < 4; i++) {
      const int mb = m0 + wr * 64 + i * 16 + qd * 4;
#pragma unroll
      for (int r = 0; r < 4; r++) {
        float v = acc[i][j][r] + bz;
        if (leaky) v = (v >= 0.f) ? v : 0.1f * v;
        if (half_out) ((_Float16*)Cout)[(size_t)(mb + r) * Dx + n] = (_Float16)v;
        else          ((float*)Cout)[(size_t)(mb + r) * Dx + n] = v;
      }
    }
  }
}

// ---------------------------------------------------------------------------
// chunkkv: per-chunk KV = K_c^T V_c stored [d][e], plus k-sum. fp16 in, fp32 out.
// wave = e-group of 16; lane = d. Outer-product: 5 LDS insts / 16 FMA.
// ---------------------------------------------------------------------------
__global__ __launch_bounds__(256) void chunkkv_kernel(
    const _Float16* __restrict__ kp, const _Float16* __restrict__ vp,
    float* __restrict__ ckv, float* __restrict__ cz)
{
  __shared__ float Ks[64 * 68];
  __shared__ float Vs[64 * 68];
  const int blk = blockIdx.x;
  const int c = blk & (NCx - 1);
  const int bh = blk / NCx;
  const int b = bh / Hx, h = bh % Hx;
  const int tid = threadIdx.x;
  const size_t rowbase = ((size_t)(b * Sx + c * 64)) * Dx + h * 64;
#pragma unroll
  for (int j = 0; j < 2; j++) {
    const int f = tid + 256 * j;
    const int t = f >> 3, c8 = f & 7;
    h8 hk = *(const h8*)&kp[rowbase + (size_t)t * Dx + c8 * 8];
    h8 hv = *(const h8*)&vp[rowbase + (size_t)t * Dx + c8 * 8];
    f4 k0 = {(float)hk[0], (float)hk[1], (float)hk[2], (float)hk[3]};
    f4 k1 = {(float)hk[4], (float)hk[5], (float)hk[6], (float)hk[7]};
    f4 v0 = {(float)hv[0], (float)hv[1], (float)hv[2], (float)hv[3]};
    f4 v1 = {(float)hv[4], (float)hv[5], (float)hv[6], (float)hv[7]};
    *(f4*)&Ks[t * 68 + c8 * 8]     = k0;
    *(f4*)&Ks[t * 68 + c8 * 8 + 4] = k1;
    *(f4*)&Vs[t * 68 + c8 * 8]     = v0;
    *(f4*)&Vs[t * 68 + c8 * 8 + 4] = v1;
  }
  __syncthreads();
  const int d = tid & 63;
  const int eg = tid >> 6;
  float acc[16];
#pragma unroll
  for (int i = 0; i < 16; i++) acc[i] = 0.f;
  float sk = 0.f;
  for (int s = 0; s < 64; s++) {
    const float kv = Ks[s * 68 + d];
    sk += kv;
#pragma unroll
    for (int i = 0; i < 4; i++) {
      const f4 vv = *(const f4*)&Vs[s * 68 + eg * 16 + i * 4];
      acc[i * 4 + 0] += kv * vv[0];
      acc[i * 4 + 1] += kv * vv[1];
      acc[i * 4 + 2] += kv * vv[2];
      acc[i * 4 + 3] += kv * vv[3];
    }
  }
  const size_t ob = (size_t)blk * 4096 + (size_t)d * 64 + eg * 16;
#pragma unroll
  for (int i = 0; i < 4; i++) {
    f4 o = {acc[i * 4 + 0], acc[i * 4 + 1], acc[i * 4 + 2], acc[i * 4 + 3]};
    *(f4*)&ckv[ob + i * 4] = o;
  }
  if (eg == 0) cz[(size_t)blk * 64 + d] = sk;
}

// ---------------------------------------------------------------------------
// prefix: element-parallel exclusive scan over 32 chunks. 512 blocks.
// ---------------------------------------------------------------------------
__global__ __launch_bounds__(256) void prefix_kernel(
    float* __restrict__ ckv, float* __restrict__ cz)
{
  const int gid = blockIdx.x * 256 + threadIdx.x;   // 0..131071
  const int bh = gid >> 12, el = gid & 4095;
  float acc = 0.f;
  for (int c = 0; c < NCx; c++) {
    const size_t idx = ((size_t)(bh * NCx + c) << 12) + el;
    const float v = ckv[idx];
    ckv[idx] = acc;
    acc += v;
  }
  if (gid < BHx * 64) {
    const int zbh = gid >> 6, d = gid & 63;
    float az = 0.f;
    for (int c = 0; c < NCx; c++) {
      const size_t zi = (size_t)(zbh * NCx + c) * 64 + d;
      const float v = cz[zi];
      cz[zi] = az;
      az += v;
    }
  }
}

// ---------------------------------------------------------------------------
// attn: all-LDS, Q register-cached, outer-product inner loops (fixed bounds).
// thread = (t = tid>>2, sg = tid&3 -> e-range sg*16..+15; A-ownership s=4*si+sg).
// Buffers: Qs (then reused as As), Xs (K then V), Ss (ckv slab [d][e]).
// Writes fp16 concat directly.
// ---------------------------------------------------------------------------
__global__ __launch_bounds__(256) void attn_kernel(
    const float* __restrict__ qp, const _Float16* __restrict__ kp,
    const _Float16* __restrict__ vp, const float* __restrict__ ckv,
    const float* __restrict__ cz, _Float16* __restrict__ concat)
{
  __shared__ float Qs[64 * 68];
  __shared__ float Xs[64 * 68];
  __shared__ float Ss[64 * 68];
  __shared__ float zs[64];
  const int blk = blockIdx.x;
  const int c = blk & (NCx - 1);
  const int bh = blk / NCx;
  const int b = bh / Hx, h = bh % Hx;
  const int tid = threadIdx.x;
  const size_t rowbase = ((size_t)(b * Sx + c * 64)) * Dx + h * 64;

  // stage Q (fp32)
#pragma unroll
  for (int j = 0; j < 4; j++) {
    const int f = tid + 256 * j;
    const int t = f >> 4, dq = f & 15;
    *(f4*)&Qs[t * 68 + dq * 4] = *(const f4*)&qp[rowbase + (size_t)t * Dx + dq * 4];
  }
  // stage K (fp16 -> fp32)
#pragma unroll
  for (int j = 0; j < 2; j++) {
    const int f = tid + 256 * j;
    const int t = f >> 3, c8 = f & 7;
    h8 hk = *(const h8*)&kp[rowbase + (size_t)t * Dx + c8 * 8];
    f4 k0 = {(float)hk[0], (float)hk[1], (float)hk[2], (float)hk[3]};
    f4 k1 = {(float)hk[4], (float)hk[5], (float)hk[6], (float)hk[7]};
    *(f4*)&Xs[t * 68 + c8 * 8]     = k0;
    *(f4*)&Xs[t * 68 + c8 * 8 + 4] = k1;
  }
  // stage S_excl slab, layout [d][e]
#pragma unroll
  for (int j = 0; j < 4; j++) {
    const int f = tid + 256 * j;
    const int d = f >> 4, eq = f & 15;
    *(f4*)&Ss[d * 68 + eq * 4] = *(const f4*)&ckv[(size_t)blk * 4096 + (size_t)d * 64 + eq * 4];
  }
  if (tid < 64) zs[tid] = cz[(size_t)blk * 64 + tid];
  __syncthreads();

  const int t = tid >> 2, sg = tid & 3;

  // Q row into registers
  f4 qreg[16];
#pragma unroll
  for (int dq = 0; dq < 16; dq++) qreg[dq] = *(const f4*)&Qs[t * 68 + dq * 4];

  // den = q . z_excl (full dot, redundant across sg — no reduce needed)
  float den = 0.f;
#pragma unroll
  for (int dq = 0; dq < 16; dq++) {
    const f4 zv = *(const f4*)&zs[dq * 4];
    den += qreg[dq][0] * zv[0] + qreg[dq][1] * zv[1] + qreg[dq][2] * zv[2] + qreg[dq][3] * zv[3];
  }
  __syncthreads();          // Qs consumed -> reuse as As
  float* As = Qs;

  // A-phase: A[t][s] for s = 4*si + sg (zero above diagonal), rowsum into rs
  float rs = 0.f;
#pragma unroll
  for (int si = 0; si < 16; si++) {
    const int s = (si << 2) + sg;
    float a = 0.f;
#pragma unroll
    for (int dq = 0; dq < 16; dq++) {
      const f4 kv = *(const f4*)&Xs[s * 68 + dq * 4];
      a += qreg[dq][0] * kv[0] + qreg[dq][1] * kv[1] + qreg[dq][2] * kv[2] + qreg[dq][3] * kv[3];
    }
    a = (s <= t) ? a : 0.f;
    rs += a;
    As[t * 68 + s] = a;
  }
  rs += __shfl_xor(rs, 1, 4);
  rs += __shfl_xor(rs, 2, 4);
  den += rs;
  __syncthreads();          // As written; K consumed -> restage V into Xs

#pragma unroll
  for (int j = 0; j < 2; j++) {
    const int f = tid + 256 * j;
    const int tt = f >> 3, c8 = f & 7;
    h8 hv = *(const h8*)&vp[rowbase + (size_t)tt * Dx + c8 * 8];
    f4 v0 = {(float)hv[0], (float)hv[1], (float)hv[2], (float)hv[3]};
    f4 v1 = {(float)hv[4], (float)hv[5], (float)hv[6], (float)hv[7]};
    *(f4*)&Xs[tt * 68 + c8 * 8]     = v0;
    *(f4*)&Xs[tt * 68 + c8 * 8 + 4] = v1;
  }
  __syncthreads();

  float num[16];
#pragma unroll
  for (int i = 0; i < 16; i++) num[i] = 0.f;

  // num += Q @ S_excl  (outer-product over d; q from regs, S rows from LDS)
#pragma unroll
  for (int d = 0; d < 64; d++) {
    const float qd = qreg[d >> 2][d & 3];
#pragma unroll
    for (int i = 0; i < 4; i++) {
      const f4 sv = *(const f4*)&Ss[d * 68 + sg * 16 + i * 4];
      num[i * 4 + 0] += qd * sv[0];
      num[i * 4 + 1] += qd * sv[1];
      num[i * 4 + 2] += qd * sv[2];
      num[i * 4 + 3] += qd * sv[3];
    }
  }
  // num += A @ V (A zero-padded above diagonal -> full fixed loop)
#pragma unroll
  for (int s = 0; s < 64; s++) {
    const float a = As[t * 68 + s];
#pragma unroll
    for (int i = 0; i < 4; i++) {
      const f4 vv = *(const f4*)&Xs[s * 68 + sg * 16 + i * 4];
      num[i * 4 + 0] += a * vv[0];
      num[i * 4 + 1] += a * vv[1];
      num[i * 4 + 2] += a * vv[2];
      num[i * 4 + 3] += a * vv[3];
    }
  }

  const float inv = 1.f / den;
  h8 h0, h1;
#pragma unroll
  for (int i = 0; i < 8; i++) h0[i] = (_Float16)(num[i] * inv);
#pragma unroll
  for (int i = 0; i < 8; i++) h1[i] = (_Float16)(num[8 + i] * inv);
  _Float16* orow = &concat[((size_t)(b * Sx + c * 64 + t)) * Dx + h * 64 + sg * 16];
  *(h8*)orow = h0;
  *(h8*)(orow + 8) = h1;
}

// ---------------------------------------------------------------------------
extern "C" void kernel_launch(void* const* d_in, const int* in_sizes, int n_in,
                              void* d_out, int out_size, void* d_ws, size_t ws_size,
                              hipStream_t stream)
{
  const float* q  = (const float*)d_in[0];
  const float* k  = (const float*)d_in[1];
  const float* v  = (const float*)d_in[2];
  const float* qm = (const float*)d_in[3];
  const float* km = (const float*)d_in[4];
  const float* vm = (const float*)d_in[5];
  const float* Wq = (const float*)d_in[6];
  const float* bq = (const float*)d_in[7];
  const float* Wk = (const float*)d_in[8];
  const float* bk = (const float*)d_in[9];
  const float* Wv = (const float*)d_in[10];
  const float* bv = (const float*)d_in[11];
  const float* Wo = (const float*)d_in[12];
  const float* bo = (const float*)d_in[13];
  float* out = (float*)d_out;

  // workspace layout (bytes); total 67.4 MB (R2's layout needed the same — OK)
  char* ws = (char*)d_ws;
  _Float16* qh  = (_Float16*)(ws);                 //  8,388,608
  _Float16* kh  = (_Float16*)(ws + 8388608);       //  8,388,608
  _Float16* vh  = (_Float16*)(ws + 16777216);      //  8,388,608
  _Float16* Wtq = (_Float16*)(ws + 25165824);      //  2,097,152
  _Float16* Wtk = (_Float16*)(ws + 27262976);
  _Float16* Wtv = (_Float16*)(ws + 29360128);
  _Float16* Wto = (_Float16*)(ws + 31457280);
  float*    qp  = (float*)   (ws + 33554432);      // 16,777,216 (fp32)
  _Float16* kp  = (_Float16*)(ws + 50331648);      //  8,388,608
  _Float16* vp  = (_Float16*)(ws + 58720256);      //  8,388,608
  float*    cz  = (float*)   (ws + 67108864);      //    262,144
  // aliases (producers strictly after consumers of the dead buffers):
  float*    ckv    = (float*)(ws + 8388608);       // 16 MB over dead kh+vh
  _Float16* concat = qh;                           //  8 MB over dead qh

  convert_in<<<4096, 256, 0, stream>>>(q, qm, qh);
  convert_in<<<4096, 256, 0, stream>>>(k, km, kh);
  convert_in<<<4096, 256, 0, stream>>>(v, vm, vh);
  convert_w<<<dim3(16, 16, 4), 256, 0, stream>>>(Wq, Wk, Wv, Wo, Wtq, Wtk, Wtv, Wto);

  dim3 ggrid(Dx / 128, Mx / 128);  // (8, 32)
  gemm_f16<<<ggrid, 256, 0, stream>>>(qh, Wtq, bq, qp, 1, 0);
  gemm_f16<<<ggrid, 256, 0, stream>>>(kh, Wtk, bk, kp, 1, 1);
  gemm_f16<<<ggrid, 256, 0, stream>>>(vh, Wtv, bv, vp, 0, 1);

  chunkkv_kernel<<<BHx * NCx, 256, 0, stream>>>(kp, vp, ckv, cz);
  prefix_kernel<<<512, 256, 0, stream>>>(ckv, cz);
  attn_kernel<<<BHx * NCx, 256, 0, stream>>>(qp, kp, vp, ckv, cz, concat);

  gemm_f16<<<ggrid, 256, 0, stream>>>(concat, Wto, bo, out, 0, 0);
}

// Round 5
// 269.996 us; speedup vs baseline: 3.5146x; 1.1557x over previous
//
#include <hip/hip_runtime.h>

// Problem constants
#define Bx    2
#define Sx    2048
#define Dx    1024
#define Hx    16
#define NCx   (Sx/64)     // 32 chunks per sequence
#define BHx   (Bx*Hx)     // 32
#define Mx    (Bx*Sx)     // 4096

typedef float    f4 __attribute__((ext_vector_type(4)));
typedef _Float16 h8 __attribute__((ext_vector_type(8)));
typedef _Float16 h4 __attribute__((ext_vector_type(4)));

// ---------------------------------------------------------------------------
// convert_w: Wt[n][k] = (fp16) W[k][n]  for 4 weights (blockIdx.z selects).
// ---------------------------------------------------------------------------
__global__ __launch_bounds__(256) void convert_w(
    const float* __restrict__ W0, const float* __restrict__ W1,
    const float* __restrict__ W2, const float* __restrict__ W3,
    _Float16* __restrict__ T0, _Float16* __restrict__ T1,
    _Float16* __restrict__ T2, _Float16* __restrict__ T3)
{
  const float* W = (blockIdx.z == 0) ? W0 : (blockIdx.z == 1) ? W1 :
                   (blockIdx.z == 2) ? W2 : W3;
  _Float16* T = (blockIdx.z == 0) ? T0 : (blockIdx.z == 1) ? T1 :
                (blockIdx.z == 2) ? T2 : T3;
  __shared__ float Ws[64 * 68];
  const int tx = threadIdx.x & 15, ty = threadIdx.x >> 4;
  const int k0 = blockIdx.y * 64, n0 = blockIdx.x * 64;
#pragma unroll
  for (int i = 0; i < 4; i++) {
    const int r = ty + 16 * i;
    *(f4*)&Ws[r * 68 + tx * 4] = *(const f4*)&W[(size_t)(k0 + r) * Dx + n0 + tx * 4];
  }
  __syncthreads();
#pragma unroll
  for (int i = 0; i < 4; i++) {
    const int n = ty + 16 * i;
    h4 o;
#pragma unroll
    for (int j = 0; j < 4; j++) o[j] = (_Float16)Ws[(tx * 4 + j) * 68 + n];
    *(h4*)&T[(size_t)(n0 + n) * Dx + k0 + tx * 4] = o;
  }
}

// ---------------------------------------------------------------------------
// gemm_f16: out[M,N] = act((A .* mask) @ Bt^T + bias). 512 threads = 8 waves
// (4x2), 2x4 frags/wave, MFMA 16x16x32_f16, 128x128 tile. A is fp32 (converted
// +masked during staging) or fp16 (a_half). blockIdx.z selects arg set (QKV
// fusion: 768 blocks = 3/CU).
// ---------------------------------------------------------------------------
struct GemmArgs {
  const void* A; const _Float16* Bt; const float* bias; const float* mask;
  void* out; int a_half, leaky, half_out;
};

__global__ __launch_bounds__(512, 4) void gemm_f16(
    GemmArgs g0, GemmArgs g1, GemmArgs g2)
{
  const GemmArgs g = (blockIdx.z == 0) ? g0 : (blockIdx.z == 1) ? g1 : g2;
  __shared__ _Float16 As[128 * 40];
  __shared__ _Float16 Bs[128 * 40];
  const int tid = threadIdx.x;
  const int m0 = blockIdx.y * 128, n0 = blockIdx.x * 128;
  const int srow = tid >> 2, sseg = tid & 3;       // staging: 8 elems/thread
  const int lane = tid & 63, wave = tid >> 6;
  const int wr = wave >> 1, wc = wave & 1;         // 4x2 wave grid
  const int lm = lane & 15, qd = lane >> 4;

  const float mf = g.mask ? g.mask[m0 + srow] : 1.f;
  const float*    gaf = (const float*)g.A    + (size_t)(m0 + srow) * Dx + sseg * 8;
  const _Float16* gah = (const _Float16*)g.A + (size_t)(m0 + srow) * Dx + sseg * 8;
  const _Float16* gb  = g.Bt + (size_t)(n0 + srow) * Dx + sseg * 8;

  f4 acc[2][4];
#pragma unroll
  for (int i = 0; i < 2; i++)
#pragma unroll
    for (int j = 0; j < 4; j++) { f4 z = {0.f, 0.f, 0.f, 0.f}; acc[i][j] = z; }

  for (int kt = 0; kt < Dx; kt += 32) {
    h8 va;
    if (g.a_half) {
      va = *(const h8*)(gah + kt);
    } else {
      const f4 x0 = *(const f4*)(gaf + kt);
      const f4 x1 = *(const f4*)(gaf + kt + 4);
      va[0] = (_Float16)(x0[0] * mf); va[1] = (_Float16)(x0[1] * mf);
      va[2] = (_Float16)(x0[2] * mf); va[3] = (_Float16)(x0[3] * mf);
      va[4] = (_Float16)(x1[0] * mf); va[5] = (_Float16)(x1[1] * mf);
      va[6] = (_Float16)(x1[2] * mf); va[7] = (_Float16)(x1[3] * mf);
    }
    const h8 vb = *(const h8*)(gb + kt);
    __syncthreads();
    *(h8*)&As[srow * 40 + sseg * 8] = va;
    *(h8*)&Bs[srow * 40 + sseg * 8] = vb;
    __syncthreads();
    h8 af[2], bf[4];
#pragma unroll
    for (int i = 0; i < 2; i++)
      af[i] = *(const h8*)&As[(wr * 32 + i * 16 + lm) * 40 + qd * 8];
#pragma unroll
    for (int j = 0; j < 4; j++)
      bf[j] = *(const h8*)&Bs[(wc * 64 + j * 16 + lm) * 40 + qd * 8];
#pragma unroll
    for (int i = 0; i < 2; i++)
#pragma unroll
      for (int j = 0; j < 4; j++)
        acc[i][j] = __builtin_amdgcn_mfma_f32_16x16x32_f16(af[i], bf[j], acc[i][j], 0, 0, 0);
  }

  // epilogue: C/D layout col=lane&15, row=quad*4+reg
#pragma unroll
  for (int j = 0; j < 4; j++) {
    const int n = n0 + wc * 64 + j * 16 + lm;
    const float bz = g.bias[n];
#pragma unroll
    for (int i = 0; i < 2; i++) {
      const int mb = m0 + wr * 32 + i * 16 + qd * 4;
#pragma unroll
      for (int r = 0; r < 4; r++) {
        float v = acc[i][j][r] + bz;
        if (g.leaky) v = (v >= 0.f) ? v : 0.1f * v;
        if (g.half_out) ((_Float16*)g.out)[(size_t)(mb + r) * Dx + n] = (_Float16)v;
        else            ((float*)g.out)[(size_t)(mb + r) * Dx + n] = v;
      }
    }
  }
}

// ---------------------------------------------------------------------------
// chunkkv: per-chunk KV = K_c^T V_c stored [d][e], plus k-sum. 512 threads.
// wave = e-group of 8; lane = d. Vs reads are whole-wave broadcasts.
// ---------------------------------------------------------------------------
__global__ __launch_bounds__(512) void chunkkv_kernel(
    const _Float16* __restrict__ kp, const _Float16* __restrict__ vp,
    float* __restrict__ ckv, float* __restrict__ cz)
{
  __shared__ float Ks[64 * 68];
  __shared__ float Vs[64 * 68];
  const int blk = blockIdx.x;
  const int c = blk & (NCx - 1);
  const int bh = blk / NCx;
  const int b = bh / Hx, h = bh % Hx;
  const int tid = threadIdx.x;
  const size_t rowbase = ((size_t)(b * Sx + c * 64)) * Dx + h * 64;
  {
    const int t = tid >> 3, c8 = tid & 7;          // 512 = 64 rows x 8 segs
    h8 hk = *(const h8*)&kp[rowbase + (size_t)t * Dx + c8 * 8];
    h8 hv = *(const h8*)&vp[rowbase + (size_t)t * Dx + c8 * 8];
    f4 k0 = {(float)hk[0], (float)hk[1], (float)hk[2], (float)hk[3]};
    f4 k1 = {(float)hk[4], (float)hk[5], (float)hk[6], (float)hk[7]};
    f4 v0 = {(float)hv[0], (float)hv[1], (float)hv[2], (float)hv[3]};
    f4 v1 = {(float)hv[4], (float)hv[5], (float)hv[6], (float)hv[7]};
    *(f4*)&Ks[t * 68 + c8 * 8]     = k0;
    *(f4*)&Ks[t * 68 + c8 * 8 + 4] = k1;
    *(f4*)&Vs[t * 68 + c8 * 8]     = v0;
    *(f4*)&Vs[t * 68 + c8 * 8 + 4] = v1;
  }
  __syncthreads();
  const int d = tid & 63;
  const int eg = tid >> 6;                          // 0..7: e-range [eg*8, +8)
  float acc[8];
#pragma unroll
  for (int i = 0; i < 8; i++) acc[i] = 0.f;
  float sk = 0.f;
  for (int s = 0; s < 64; s++) {
    const float kv = Ks[s * 68 + d];
    sk += kv;
#pragma unroll
    for (int i = 0; i < 2; i++) {
      const f4 vv = *(const f4*)&Vs[s * 68 + eg * 8 + i * 4];
      acc[i * 4 + 0] += kv * vv[0];
      acc[i * 4 + 1] += kv * vv[1];
      acc[i * 4 + 2] += kv * vv[2];
      acc[i * 4 + 3] += kv * vv[3];
    }
  }
  const size_t ob = (size_t)blk * 4096 + (size_t)d * 64 + eg * 8;
#pragma unroll
  for (int i = 0; i < 2; i++) {
    f4 o = {acc[i * 4 + 0], acc[i * 4 + 1], acc[i * 4 + 2], acc[i * 4 + 3]};
    *(f4*)&ckv[ob + i * 4] = o;
  }
  if (eg == 0) cz[(size_t)blk * 64 + d] = sk;
}

// ---------------------------------------------------------------------------
// prefix: element-parallel exclusive scan over 32 chunks. 512 blocks x 256.
// ---------------------------------------------------------------------------
__global__ __launch_bounds__(256) void prefix_kernel(
    float* __restrict__ ckv, float* __restrict__ cz)
{
  const int gid = blockIdx.x * 256 + threadIdx.x;   // 0..131071
  const int bh = gid >> 12, el = gid & 4095;
  float acc = 0.f;
  for (int c = 0; c < NCx; c++) {
    const size_t idx = ((size_t)(bh * NCx + c) << 12) + el;
    const float v = ckv[idx];
    ckv[idx] = acc;
    acc += v;
  }
  if (gid < BHx * 64) {
    const int zbh = gid >> 6, d = gid & 63;
    float az = 0.f;
    for (int c = 0; c < NCx; c++) {
      const size_t zi = (size_t)(zbh * NCx + c) * 64 + d;
      const float v = cz[zi];
      cz[zi] = az;
      az += v;
    }
  }
}

// ---------------------------------------------------------------------------
// attn: 512 threads (8 waves). thread = (t = tid>>3, sg = tid&7 -> e-range
// sg*8..+8; A-ownership s = 8*si+sg). Qs reused as As; Xs holds K then V.
// ---------------------------------------------------------------------------
__global__ __launch_bounds__(512) void attn_kernel(
    const float* __restrict__ qp, const _Float16* __restrict__ kp,
    const _Float16* __restrict__ vp, const float* __restrict__ ckv,
    const float* __restrict__ cz, _Float16* __restrict__ concat)
{
  __shared__ float Qs[64 * 68];
  __shared__ float Xs[64 * 68];
  __shared__ float Ss[64 * 68];
  __shared__ float zs[64];
  const int blk = blockIdx.x;
  const int c = blk & (NCx - 1);
  const int bh = blk / NCx;
  const int b = bh / Hx, h = bh % Hx;
  const int tid = threadIdx.x;
  const size_t rowbase = ((size_t)(b * Sx + c * 64)) * Dx + h * 64;

  // stage Q (fp32): 1024 f4 over 512 threads
#pragma unroll
  for (int j = 0; j < 2; j++) {
    const int f = tid + 512 * j;
    const int t = f >> 4, dq = f & 15;
    *(f4*)&Qs[t * 68 + dq * 4] = *(const f4*)&qp[rowbase + (size_t)t * Dx + dq * 4];
  }
  // stage K (fp16 -> fp32): 512 h8
  {
    const int t = tid >> 3, c8 = tid & 7;
    h8 hk = *(const h8*)&kp[rowbase + (size_t)t * Dx + c8 * 8];
    f4 k0 = {(float)hk[0], (float)hk[1], (float)hk[2], (float)hk[3]};
    f4 k1 = {(float)hk[4], (float)hk[5], (float)hk[6], (float)hk[7]};
    *(f4*)&Xs[t * 68 + c8 * 8]     = k0;
    *(f4*)&Xs[t * 68 + c8 * 8 + 4] = k1;
  }
  // stage S_excl slab [d][e]
#pragma unroll
  for (int j = 0; j < 2; j++) {
    const int f = tid + 512 * j;
    const int d = f >> 4, eq = f & 15;
    *(f4*)&Ss[d * 68 + eq * 4] = *(const f4*)&ckv[(size_t)blk * 4096 + (size_t)d * 64 + eq * 4];
  }
  if (tid < 64) zs[tid] = cz[(size_t)blk * 64 + tid];
  __syncthreads();

  const int t = tid >> 3, sg = tid & 7;

  // Q row into registers (broadcast reads)
  f4 qreg[16];
#pragma unroll
  for (int dq = 0; dq < 16; dq++) qreg[dq] = *(const f4*)&Qs[t * 68 + dq * 4];

  // den = q . z_excl (redundant across sg)
  float den = 0.f;
#pragma unroll
  for (int dq = 0; dq < 16; dq++) {
    const f4 zv = *(const f4*)&zs[dq * 4];
    den += qreg[dq][0] * zv[0] + qreg[dq][1] * zv[1] + qreg[dq][2] * zv[2] + qreg[dq][3] * zv[3];
  }
  __syncthreads();          // Qs consumed -> reuse as As
  float* As = Qs;

  // A-phase: A[t][s] for s = 8*si + sg, zero above diagonal; rowsum
  float rs = 0.f;
#pragma unroll
  for (int si = 0; si < 8; si++) {
    const int s = (si << 3) + sg;
    float a = 0.f;
#pragma unroll
    for (int dq = 0; dq < 16; dq++) {
      const f4 kv = *(const f4*)&Xs[s * 68 + dq * 4];
      a += qreg[dq][0] * kv[0] + qreg[dq][1] * kv[1] + qreg[dq][2] * kv[2] + qreg[dq][3] * kv[3];
    }
    a = (s <= t) ? a : 0.f;
    rs += a;
    As[t * 68 + s] = a;
  }
  rs += __shfl_xor(rs, 1, 8);
  rs += __shfl_xor(rs, 2, 8);
  rs += __shfl_xor(rs, 4, 8);
  den += rs;
  __syncthreads();          // As complete; K consumed -> restage V into Xs

  {
    const int tt = tid >> 3, c8 = tid & 7;
    h8 hv = *(const h8*)&vp[rowbase + (size_t)tt * Dx + c8 * 8];
    f4 v0 = {(float)hv[0], (float)hv[1], (float)hv[2], (float)hv[3]};
    f4 v1 = {(float)hv[4], (float)hv[5], (float)hv[6], (float)hv[7]};
    *(f4*)&Xs[tt * 68 + c8 * 8]     = v0;
    *(f4*)&Xs[tt * 68 + c8 * 8 + 4] = v1;
  }
  __syncthreads();

  float num[8];
#pragma unroll
  for (int i = 0; i < 8; i++) num[i] = 0.f;

  // num += Q @ S_excl (outer product over d)
#pragma unroll
  for (int d = 0; d < 64; d++) {
    const float qd = qreg[d >> 2][d & 3];
#pragma unroll
    for (int i = 0; i < 2; i++) {
      const f4 sv = *(const f4*)&Ss[d * 68 + sg * 8 + i * 4];
      num[i * 4 + 0] += qd * sv[0];
      num[i * 4 + 1] += qd * sv[1];
      num[i * 4 + 2] += qd * sv[2];
      num[i * 4 + 3] += qd * sv[3];
    }
  }
  // num += A @ V (A zero-padded above diagonal -> fixed loop)
#pragma unroll
  for (int s = 0; s < 64; s++) {
    const float a = As[t * 68 + s];
#pragma unroll
    for (int i = 0; i < 2; i++) {
      const f4 vv = *(const f4*)&Xs[s * 68 + sg * 8 + i * 4];
      num[i * 4 + 0] += a * vv[0];
      num[i * 4 + 1] += a * vv[1];
      num[i * 4 + 2] += a * vv[2];
      num[i * 4 + 3] += a * vv[3];
    }
  }

  const float inv = 1.f / den;
  h8 ho;
#pragma unroll
  for (int i = 0; i < 8; i++) ho[i] = (_Float16)(num[i] * inv);
  *(h8*)&concat[((size_t)(b * Sx + c * 64 + t)) * Dx + h * 64 + sg * 8] = ho;
}

// ---------------------------------------------------------------------------
extern "C" void kernel_launch(void* const* d_in, const int* in_sizes, int n_in,
                              void* d_out, int out_size, void* d_ws, size_t ws_size,
                              hipStream_t stream)
{
  const float* q  = (const float*)d_in[0];
  const float* k  = (const float*)d_in[1];
  const float* v  = (const float*)d_in[2];
  const float* qm = (const float*)d_in[3];
  const float* km = (const float*)d_in[4];
  const float* vm = (const float*)d_in[5];
  const float* Wq = (const float*)d_in[6];
  const float* bq = (const float*)d_in[7];
  const float* Wk = (const float*)d_in[8];
  const float* bk = (const float*)d_in[9];
  const float* Wv = (const float*)d_in[10];
  const float* bv = (const float*)d_in[11];
  const float* Wo = (const float*)d_in[12];
  const float* bo = (const float*)d_in[13];
  float* out = (float*)d_out;

  // workspace layout (bytes), total 65.3 MB (< proven 67.4 MB)
  char* ws = (char*)d_ws;
  _Float16* Wtq = (_Float16*)(ws);                 // 2 MB each
  _Float16* Wtk = (_Float16*)(ws + 2097152);
  _Float16* Wtv = (_Float16*)(ws + 4194304);
  _Float16* Wto = (_Float16*)(ws + 6291456);
  float*    qp  = (float*)   (ws + 8388608);       // 16 MB fp32
  _Float16* kp  = (_Float16*)(ws + 25165824);      //  8 MB
  _Float16* vp  = (_Float16*)(ws + 33554432);      //  8 MB
  float*    ckv = (float*)   (ws + 41943040);      // 16 MB
  float*    cz  = (float*)   (ws + 58720256);      // 256 KB
  _Float16* concat = (_Float16*)(ws + 58982400);   //  8 MB

  convert_w<<<dim3(16, 16, 4), 256, 0, stream>>>(Wq, Wk, Wv, Wo, Wtq, Wtk, Wtv, Wto);

  GemmArgs gq = { q, Wtq, bq, qm, qp, 0, 1, 0 };
  GemmArgs gk = { k, Wtk, bk, km, kp, 0, 1, 1 };
  GemmArgs gv = { v, Wtv, bv, vm, vp, 0, 0, 1 };
  gemm_f16<<<dim3(Dx / 128, Mx / 128, 3), 512, 0, stream>>>(gq, gk, gv);

  chunkkv_kernel<<<BHx * NCx, 512, 0, stream>>>(kp, vp, ckv, cz);
  prefix_kernel<<<512, 256, 0, stream>>>(ckv, cz);
  attn_kernel<<<BHx * NCx, 512, 0, stream>>>(qp, kp, vp, ckv, cz, concat);

  GemmArgs go = { concat, Wto, bo, nullptr, out, 1, 0, 0 };
  gemm_f16<<<dim3(Dx / 128, Mx / 128, 1), 512, 0, stream>>>(go, go, go);
}

// Round 6
// 251.035 us; speedup vs baseline: 3.7801x; 1.0755x over previous
//
#include <hip/hip_runtime.h>

// Problem constants
#define Bx    2
#define Sx    2048
#define Dx    1024
#define Hx    16
#define NCx   (Sx/64)     // 32 chunks per sequence
#define BHx   (Bx*Hx)     // 32
#define Mx    (Bx*Sx)     // 4096

typedef float    f4 __attribute__((ext_vector_type(4)));
typedef _Float16 h8 __attribute__((ext_vector_type(8)));
typedef _Float16 h4 __attribute__((ext_vector_type(4)));

// async global->LDS, 16B per lane. LDS dest = wave-uniform base + lane*16.
__device__ __forceinline__ void gl2lds16(const _Float16* g, _Float16* l) {
  __builtin_amdgcn_global_load_lds(
      (const __attribute__((address_space(1))) void*)g,
      (__attribute__((address_space(3))) void*)l, 16, 0, 0);
}

// ---------------------------------------------------------------------------
// convert_in: xh = (fp16)(x * mask[row]) for q,k,v in one dispatch (y selects).
// ---------------------------------------------------------------------------
__global__ __launch_bounds__(256) void convert_in(
    const float* __restrict__ q, const float* __restrict__ k,
    const float* __restrict__ v, const float* __restrict__ qm,
    const float* __restrict__ km, const float* __restrict__ vm,
    _Float16* __restrict__ qh, _Float16* __restrict__ kh,
    _Float16* __restrict__ vh)
{
  const int z = blockIdx.y;
  const float* x = (z == 0) ? q : (z == 1) ? k : v;
  const float* m = (z == 0) ? qm : (z == 1) ? km : vm;
  _Float16*    o = (z == 0) ? qh : (z == 1) ? kh : vh;
  const int i4 = blockIdx.x * 256 + threadIdx.x;   // 0..1048575
  const f4 vv = *(const f4*)(x + (size_t)i4 * 4);
  const float mf = m[i4 >> 8];
  h4 r;
  r[0] = (_Float16)(vv[0] * mf);
  r[1] = (_Float16)(vv[1] * mf);
  r[2] = (_Float16)(vv[2] * mf);
  r[3] = (_Float16)(vv[3] * mf);
  *(h4*)(o + (size_t)i4 * 4) = r;
}

// ---------------------------------------------------------------------------
// convert_w: Wt[n][k] = (fp16) W[k][n]  for 4 weights (blockIdx.z selects).
// ---------------------------------------------------------------------------
__global__ __launch_bounds__(256) void convert_w(
    const float* __restrict__ W0, const float* __restrict__ W1,
    const float* __restrict__ W2, const float* __restrict__ W3,
    _Float16* __restrict__ T0, _Float16* __restrict__ T1,
    _Float16* __restrict__ T2, _Float16* __restrict__ T3)
{
  const float* W = (blockIdx.z == 0) ? W0 : (blockIdx.z == 1) ? W1 :
                   (blockIdx.z == 2) ? W2 : W3;
  _Float16* T = (blockIdx.z == 0) ? T0 : (blockIdx.z == 1) ? T1 :
                (blockIdx.z == 2) ? T2 : T3;
  __shared__ float Ws[64 * 68];
  const int tx = threadIdx.x & 15, ty = threadIdx.x >> 4;
  const int k0 = blockIdx.y * 64, n0 = blockIdx.x * 64;
#pragma unroll
  for (int i = 0; i < 4; i++) {
    const int r = ty + 16 * i;
    *(f4*)&Ws[r * 68 + tx * 4] = *(const f4*)&W[(size_t)(k0 + r) * Dx + n0 + tx * 4];
  }
  __syncthreads();
#pragma unroll
  for (int i = 0; i < 4; i++) {
    const int n = ty + 16 * i;
    h4 o;
#pragma unroll
    for (int j = 0; j < 4; j++) o[j] = (_Float16)Ws[(tx * 4 + j) * 68 + n];
    *(h4*)&T[(size_t)(n0 + n) * Dx + k0 + tx * 4] = o;
  }
}

// ---------------------------------------------------------------------------
// gemm_f16: out[M,N] = act(A @ Bt^T + bias), A fp16 [M,1024], Bt fp16 [N][1024].
// m97-style: global_load_lds 16B staging, XOR-swizzled seg layout, BK=64,
// BM=128 x BN tile, 512 threads = 8 waves (WR x WC), MFMA 16x16x32_f16.
// LDS rows = 64 halves (128B, full bank cycle); seg_phys = seg ^ (row&7) makes
// both staging (sequential by construction) and frag reads conflict-free.
// ---------------------------------------------------------------------------
struct GArgs {
  const _Float16* A; const _Float16* Bt; const float* bias;
  void* out; int leaky, half_out;
};

template<int BN, int WR, int WC>
__global__ __launch_bounds__(512, 4) void gemm_f16(GArgs g0, GArgs g1, GArgs g2)
{
  const GArgs g = (blockIdx.z == 0) ? g0 : (blockIdx.z == 1) ? g1 : g2;
  constexpr int FM = 128 / WR / 16;
  constexpr int FN = BN / WC / 16;
  __shared__ _Float16 As[128 * 64];
  __shared__ _Float16 Bs[BN * 64];
  const int tid = threadIdx.x;
  const int m0 = blockIdx.y * 128, n0 = blockIdx.x * BN;
  const int lane = tid & 63, wave = tid >> 6;
  const int lm = lane & 15, qd = lane >> 4;
  const int wr = wave % WR, wc = wave / WR;
  const int wm0 = wr * (128 / WR), wn0 = wc * (BN / WC);
  // staging: lane -> (row lane>>3, seg (lane&7)^(lane>>3)); 1KB per wave-inst
  const int srow = lane >> 3;
  const int sseg = (lane & 7) ^ srow;
  const _Float16* gA = g.A  + (size_t)(m0 + srow) * Dx + sseg * 8;
  const _Float16* gB = g.Bt + (size_t)(n0 + srow) * Dx + sseg * 8;

  f4 acc[FM][FN];
#pragma unroll
  for (int i = 0; i < FM; i++)
#pragma unroll
    for (int j = 0; j < FN; j++) { f4 z = {0.f, 0.f, 0.f, 0.f}; acc[i][j] = z; }

  for (int kt = 0; kt < Dx; kt += 64) {
    __syncthreads();                       // previous tile's reads complete
#pragma unroll
    for (int u = 0; u < 2; u++) {          // A: 16 KB = 16 insts, 2/wave
      const int t = wave * 2 + u;
      gl2lds16(gA + (size_t)(t * 8) * Dx + kt, &As[t * 512]);
    }
#pragma unroll
    for (int u = 0; u < BN / 64; u++) {    // B: BN/8 insts, BN/64 per wave
      const int t = wave * (BN / 64) + u;
      gl2lds16(gB + (size_t)(t * 8) * Dx + kt, &Bs[t * 512]);
    }
    __syncthreads();                       // drains vmcnt -> LDS valid
#pragma unroll
    for (int kk = 0; kk < 2; kk++) {
      const int sp = ((kk * 4 + qd) ^ (lm & 7)) * 8;
      h8 af[FM];
#pragma unroll
      for (int i = 0; i < FM; i++)
        af[i] = *(const h8*)&As[(wm0 + i * 16 + lm) * 64 + sp];
#pragma unroll
      for (int j = 0; j < FN; j++) {
        const h8 bf = *(const h8*)&Bs[(wn0 + j * 16 + lm) * 64 + sp];
#pragma unroll
        for (int i = 0; i < FM; i++)
          acc[i][j] = __builtin_amdgcn_mfma_f32_16x16x32_f16(af[i], bf, acc[i][j], 0, 0, 0);
      }
    }
  }

  // epilogue: C/D layout col=lane&15, row=quad*4+reg
#pragma unroll
  for (int j = 0; j < FN; j++) {
    const int n = n0 + wn0 + j * 16 + lm;
    const float bz = g.bias[n];
#pragma unroll
    for (int i = 0; i < FM; i++) {
      const int mb = m0 + wm0 + i * 16 + qd * 4;
#pragma unroll
      for (int r = 0; r < 4; r++) {
        float v = acc[i][j][r] + bz;
        if (g.leaky) v = (v >= 0.f) ? v : 0.1f * v;
        if (g.half_out) ((_Float16*)g.out)[(size_t)(mb + r) * Dx + n] = (_Float16)v;
        else            ((float*)g.out)[(size_t)(mb + r) * Dx + n] = v;
      }
    }
  }
}

// ---------------------------------------------------------------------------
// chunkkv: per-chunk KV = K_c^T V_c stored [d][e], plus k-sum. 512 threads.
// ---------------------------------------------------------------------------
__global__ __launch_bounds__(512) void chunkkv_kernel(
    const _Float16* __restrict__ kp, const _Float16* __restrict__ vp,
    float* __restrict__ ckv, float* __restrict__ cz)
{
  __shared__ float Ks[64 * 68];
  __shared__ float Vs[64 * 68];
  const int blk = blockIdx.x;
  const int c = blk & (NCx - 1);
  const int bh = blk / NCx;
  const int b = bh / Hx, h = bh % Hx;
  const int tid = threadIdx.x;
  const size_t rowbase = ((size_t)(b * Sx + c * 64)) * Dx + h * 64;
  {
    const int t = tid >> 3, c8 = tid & 7;
    h8 hk = *(const h8*)&kp[rowbase + (size_t)t * Dx + c8 * 8];
    h8 hv = *(const h8*)&vp[rowbase + (size_t)t * Dx + c8 * 8];
    f4 k0 = {(float)hk[0], (float)hk[1], (float)hk[2], (float)hk[3]};
    f4 k1 = {(float)hk[4], (float)hk[5], (float)hk[6], (float)hk[7]};
    f4 v0 = {(float)hv[0], (float)hv[1], (float)hv[2], (float)hv[3]};
    f4 v1 = {(float)hv[4], (float)hv[5], (float)hv[6], (float)hv[7]};
    *(f4*)&Ks[t * 68 + c8 * 8]     = k0;
    *(f4*)&Ks[t * 68 + c8 * 8 + 4] = k1;
    *(f4*)&Vs[t * 68 + c8 * 8]     = v0;
    *(f4*)&Vs[t * 68 + c8 * 8 + 4] = v1;
  }
  __syncthreads();
  const int d = tid & 63;
  const int eg = tid >> 6;                          // 0..7: e-range [eg*8, +8)
  float acc[8];
#pragma unroll
  for (int i = 0; i < 8; i++) acc[i] = 0.f;
  float sk = 0.f;
  for (int s = 0; s < 64; s++) {
    const float kv = Ks[s * 68 + d];
    sk += kv;
#pragma unroll
    for (int i = 0; i < 2; i++) {
      const f4 vv = *(const f4*)&Vs[s * 68 + eg * 8 + i * 4];
      acc[i * 4 + 0] += kv * vv[0];
      acc[i * 4 + 1] += kv * vv[1];
      acc[i * 4 + 2] += kv * vv[2];
      acc[i * 4 + 3] += kv * vv[3];
    }
  }
  const size_t ob = (size_t)blk * 4096 + (size_t)d * 64 + eg * 8;
#pragma unroll
  for (int i = 0; i < 2; i++) {
    f4 o = {acc[i * 4 + 0], acc[i * 4 + 1], acc[i * 4 + 2], acc[i * 4 + 3]};
    *(f4*)&ckv[ob + i * 4] = o;
  }
  if (eg == 0) cz[(size_t)blk * 64 + d] = sk;
}

// ---------------------------------------------------------------------------
// prefix: element-parallel exclusive scan over 32 chunks. 512 blocks x 256.
// ---------------------------------------------------------------------------
__global__ __launch_bounds__(256) void prefix_kernel(
    float* __restrict__ ckv, float* __restrict__ cz)
{
  const int gid = blockIdx.x * 256 + threadIdx.x;   // 0..131071
  const int bh = gid >> 12, el = gid & 4095;
  float acc = 0.f;
  for (int c = 0; c < NCx; c++) {
    const size_t idx = ((size_t)(bh * NCx + c) << 12) + el;
    const float v = ckv[idx];
    ckv[idx] = acc;
    acc += v;
  }
  if (gid < BHx * 64) {
    const int zbh = gid >> 6, d = gid & 63;
    float az = 0.f;
    for (int c = 0; c < NCx; c++) {
      const size_t zi = (size_t)(zbh * NCx + c) * 64 + d;
      const float v = cz[zi];
      cz[zi] = az;
      az += v;
    }
  }
}

// ---------------------------------------------------------------------------
// attn: 512 threads (8 waves). thread = (t = tid>>3, sg = tid&7 -> e-range
// sg*8..+8; A-ownership s = 8*si+sg). Qs reused as As; Xs holds K then V.
// qp now fp16.
// ---------------------------------------------------------------------------
__global__ __launch_bounds__(512) void attn_kernel(
    const _Float16* __restrict__ qp, const _Float16* __restrict__ kp,
    const _Float16* __restrict__ vp, const float* __restrict__ ckv,
    const float* __restrict__ cz, _Float16* __restrict__ concat)
{
  __shared__ float Qs[64 * 68];
  __shared__ float Xs[64 * 68];
  __shared__ float Ss[64 * 68];
  __shared__ float zs[64];
  const int blk = blockIdx.x;
  const int c = blk & (NCx - 1);
  const int bh = blk / NCx;
  const int b = bh / Hx, h = bh % Hx;
  const int tid = threadIdx.x;
  const size_t rowbase = ((size_t)(b * Sx + c * 64)) * Dx + h * 64;

  // stage Q and K (fp16 -> fp32)
  {
    const int t = tid >> 3, c8 = tid & 7;
    h8 hq = *(const h8*)&qp[rowbase + (size_t)t * Dx + c8 * 8];
    h8 hk = *(const h8*)&kp[rowbase + (size_t)t * Dx + c8 * 8];
    f4 q0 = {(float)hq[0], (float)hq[1], (float)hq[2], (float)hq[3]};
    f4 q1 = {(float)hq[4], (float)hq[5], (float)hq[6], (float)hq[7]};
    f4 k0 = {(float)hk[0], (float)hk[1], (float)hk[2], (float)hk[3]};
    f4 k1 = {(float)hk[4], (float)hk[5], (float)hk[6], (float)hk[7]};
    *(f4*)&Qs[t * 68 + c8 * 8]     = q0;
    *(f4*)&Qs[t * 68 + c8 * 8 + 4] = q1;
    *(f4*)&Xs[t * 68 + c8 * 8]     = k0;
    *(f4*)&Xs[t * 68 + c8 * 8 + 4] = k1;
  }
  // stage S_excl slab [d][e]
#pragma unroll
  for (int j = 0; j < 2; j++) {
    const int f = tid + 512 * j;
    const int d = f >> 4, eq = f & 15;
    *(f4*)&Ss[d * 68 + eq * 4] = *(const f4*)&ckv[(size_t)blk * 4096 + (size_t)d * 64 + eq * 4];
  }
  if (tid < 64) zs[tid] = cz[(size_t)blk * 64 + tid];
  __syncthreads();

  const int t = tid >> 3, sg = tid & 7;

  f4 qreg[16];
#pragma unroll
  for (int dq = 0; dq < 16; dq++) qreg[dq] = *(const f4*)&Qs[t * 68 + dq * 4];

  float den = 0.f;
#pragma unroll
  for (int dq = 0; dq < 16; dq++) {
    const f4 zv = *(const f4*)&zs[dq * 4];
    den += qreg[dq][0] * zv[0] + qreg[dq][1] * zv[1] + qreg[dq][2] * zv[2] + qreg[dq][3] * zv[3];
  }
  __syncthreads();          // Qs consumed -> reuse as As
  float* As = Qs;

  float rs = 0.f;
#pragma unroll
  for (int si = 0; si < 8; si++) {
    const int s = (si << 3) + sg;
    float a = 0.f;
#pragma unroll
    for (int dq = 0; dq < 16; dq++) {
      const f4 kv = *(const f4*)&Xs[s * 68 + dq * 4];
      a += qreg[dq][0] * kv[0] + qreg[dq][1] * kv[1] + qreg[dq][2] * kv[2] + qreg[dq][3] * kv[3];
    }
    a = (s <= t) ? a : 0.f;
    rs += a;
    As[t * 68 + s] = a;
  }
  rs += __shfl_xor(rs, 1, 8);
  rs += __shfl_xor(rs, 2, 8);
  rs += __shfl_xor(rs, 4, 8);
  den += rs;
  __syncthreads();          // As complete; K consumed -> restage V into Xs

  {
    const int tt = tid >> 3, c8 = tid & 7;
    h8 hv = *(const h8*)&vp[rowbase + (size_t)tt * Dx + c8 * 8];
    f4 v0 = {(float)hv[0], (float)hv[1], (float)hv[2], (float)hv[3]};
    f4 v1 = {(float)hv[4], (float)hv[5], (float)hv[6], (float)hv[7]};
    *(f4*)&Xs[tt * 68 + c8 * 8]     = v0;
    *(f4*)&Xs[tt * 68 + c8 * 8 + 4] = v1;
  }
  __syncthreads();

  float num[8];
#pragma unroll
  for (int i = 0; i < 8; i++) num[i] = 0.f;

#pragma unroll
  for (int d = 0; d < 64; d++) {
    const float qd = qreg[d >> 2][d & 3];
#pragma unroll
    for (int i = 0; i < 2; i++) {
      const f4 sv = *(const f4*)&Ss[d * 68 + sg * 8 + i * 4];
      num[i * 4 + 0] += qd * sv[0];
      num[i * 4 + 1] += qd * sv[1];
      num[i * 4 + 2] += qd * sv[2];
      num[i * 4 + 3] += qd * sv[3];
    }
  }
#pragma unroll
  for (int s = 0; s < 64; s++) {
    const float a = As[t * 68 + s];
#pragma unroll
    for (int i = 0; i < 2; i++) {
      const f4 vv = *(const f4*)&Xs[s * 68 + sg * 8 + i * 4];
      num[i * 4 + 0] += a * vv[0];
      num[i * 4 + 1] += a * vv[1];
      num[i * 4 + 2] += a * vv[2];
      num[i * 4 + 3] += a * vv[3];
    }
  }

  const float inv = 1.f / den;
  h8 ho;
#pragma unroll
  for (int i = 0; i < 8; i++) ho[i] = (_Float16)(num[i] * inv);
  *(h8*)&concat[((size_t)(b * Sx + c * 64 + t)) * Dx + h * 64 + sg * 8] = ho;
}

// ---------------------------------------------------------------------------
extern "C" void kernel_launch(void* const* d_in, const int* in_sizes, int n_in,
                              void* d_out, int out_size, void* d_ws, size_t ws_size,
                              hipStream_t stream)
{
  const float* q  = (const float*)d_in[0];
  const float* k  = (const float*)d_in[1];
  const float* v  = (const float*)d_in[2];
  const float* qm = (const float*)d_in[3];
  const float* km = (const float*)d_in[4];
  const float* vm = (const float*)d_in[5];
  const float* Wq = (const float*)d_in[6];
  const float* bq = (const float*)d_in[7];
  const float* Wk = (const float*)d_in[8];
  const float* bk = (const float*)d_in[9];
  const float* Wv = (const float*)d_in[10];
  const float* bv = (const float*)d_in[11];
  const float* Wo = (const float*)d_in[12];
  const float* bo = (const float*)d_in[13];
  float* out = (float*)d_out;

  // workspace layout (bytes), total 56.25 MB (< proven 65.3 MB).
  // qh/kh [0..16M) die after QKV gemm -> ckv overlays; vh [16M..24M) dies
  // after QKV gemm -> concat overlays (chunkkv/attn run strictly after).
  char* ws = (char*)d_ws;
  _Float16* qh  = (_Float16*)(ws);                 //  8 MB
  _Float16* kh  = (_Float16*)(ws + 8388608);       //  8 MB
  _Float16* vh  = (_Float16*)(ws + 16777216);      //  8 MB
  _Float16* Wtq = (_Float16*)(ws + 25165824);      //  2 MB each
  _Float16* Wtk = (_Float16*)(ws + 27262976);
  _Float16* Wtv = (_Float16*)(ws + 29360128);
  _Float16* Wto = (_Float16*)(ws + 31457280);
  _Float16* qp  = (_Float16*)(ws + 33554432);      //  8 MB fp16 now
  _Float16* kp  = (_Float16*)(ws + 41943040);      //  8 MB
  _Float16* vp  = (_Float16*)(ws + 50331648);      //  8 MB
  float*    cz  = (float*)   (ws + 58720256);      //  256 KB
  float*    ckv    = (float*)ws;                   // 16 MB over dead qh+kh
  _Float16* concat = vh;                           //  8 MB over dead vh

  convert_in<<<dim3(4096, 3), 256, 0, stream>>>(q, k, v, qm, km, vm, qh, kh, vh);
  convert_w<<<dim3(16, 16, 4), 256, 0, stream>>>(Wq, Wk, Wv, Wo, Wtq, Wtk, Wtv, Wto);

  GArgs gq = { qh, Wtq, bq, qp, 1, 1 };
  GArgs gk = { kh, Wtk, bk, kp, 1, 1 };
  GArgs gv = { vh, Wtv, bv, vp, 0, 1 };
  gemm_f16<256, 2, 4><<<dim3(Dx / 256, Mx / 128, 3), 512, 0, stream>>>(gq, gk, gv);

  chunkkv_kernel<<<BHx * NCx, 512, 0, stream>>>(kp, vp, ckv, cz);
  prefix_kernel<<<512, 256, 0, stream>>>(ckv, cz);
  attn_kernel<<<BHx * NCx, 512, 0, stream>>>(qp, kp, vp, ckv, cz, concat);

  GArgs go = { concat, Wto, bo, out, 0, 0 };
  gemm_f16<128, 4, 2><<<dim3(Dx / 128, Mx / 128, 1), 512, 0, stream>>>(go, go, go);
}

// Round 7
// 204.402 us; speedup vs baseline: 4.6425x; 1.2281x over previous
//
#include <hip/hip_runtime.h>

// Problem constants
#define Bx    2
#define Sx    2048
#define Dx    1024
#define Hx    16
#define NCx   (Sx/64)     // 32 chunks per sequence
#define BHx   (Bx*Hx)     // 32
#define Mx    (Bx*Sx)     // 4096

typedef float    f4 __attribute__((ext_vector_type(4)));
typedef _Float16 h8 __attribute__((ext_vector_type(8)));
typedef _Float16 h4 __attribute__((ext_vector_type(4)));

// async global->LDS, 16B per lane. LDS dest = wave-uniform base + lane*16.
__device__ __forceinline__ void gl2lds16(const _Float16* g, _Float16* l) {
  __builtin_amdgcn_global_load_lds(
      (const __attribute__((address_space(1))) void*)g,
      (__attribute__((address_space(3))) void*)l, 16, 0, 0);
}

// ---------------------------------------------------------------------------
// convert_in: xh = (fp16)(x * mask[row]) for q,k,v in one dispatch (y selects).
// ---------------------------------------------------------------------------
__global__ __launch_bounds__(256) void convert_in(
    const float* __restrict__ q, const float* __restrict__ k,
    const float* __restrict__ v, const float* __restrict__ qm,
    const float* __restrict__ km, const float* __restrict__ vm,
    _Float16* __restrict__ qh, _Float16* __restrict__ kh,
    _Float16* __restrict__ vh)
{
  const int z = blockIdx.y;
  const float* x = (z == 0) ? q : (z == 1) ? k : v;
  const float* m = (z == 0) ? qm : (z == 1) ? km : vm;
  _Float16*    o = (z == 0) ? qh : (z == 1) ? kh : vh;
  const int i4 = blockIdx.x * 256 + threadIdx.x;   // 0..1048575
  const f4 vv = *(const f4*)(x + (size_t)i4 * 4);
  const float mf = m[i4 >> 8];
  h4 r;
  r[0] = (_Float16)(vv[0] * mf);
  r[1] = (_Float16)(vv[1] * mf);
  r[2] = (_Float16)(vv[2] * mf);
  r[3] = (_Float16)(vv[3] * mf);
  *(h4*)(o + (size_t)i4 * 4) = r;
}

// ---------------------------------------------------------------------------
// convert_w: Wt[n][k] = (fp16) W[k][n]  for 4 weights (blockIdx.z selects).
// ---------------------------------------------------------------------------
__global__ __launch_bounds__(256) void convert_w(
    const float* __restrict__ W0, const float* __restrict__ W1,
    const float* __restrict__ W2, const float* __restrict__ W3,
    _Float16* __restrict__ T0, _Float16* __restrict__ T1,
    _Float16* __restrict__ T2, _Float16* __restrict__ T3)
{
  const float* W = (blockIdx.z == 0) ? W0 : (blockIdx.z == 1) ? W1 :
                   (blockIdx.z == 2) ? W2 : W3;
  _Float16* T = (blockIdx.z == 0) ? T0 : (blockIdx.z == 1) ? T1 :
                (blockIdx.z == 2) ? T2 : T3;
  __shared__ float Ws[64 * 68];
  const int tx = threadIdx.x & 15, ty = threadIdx.x >> 4;
  const int k0 = blockIdx.y * 64, n0 = blockIdx.x * 64;
#pragma unroll
  for (int i = 0; i < 4; i++) {
    const int r = ty + 16 * i;
    *(f4*)&Ws[r * 68 + tx * 4] = *(const f4*)&W[(size_t)(k0 + r) * Dx + n0 + tx * 4];
  }
  __syncthreads();
#pragma unroll
  for (int i = 0; i < 4; i++) {
    const int n = ty + 16 * i;
    h4 o;
#pragma unroll
    for (int j = 0; j < 4; j++) o[j] = (_Float16)Ws[(tx * 4 + j) * 68 + n];
    *(h4*)&T[(size_t)(n0 + n) * Dx + k0 + tx * 4] = o;
  }
}

// ---------------------------------------------------------------------------
// gemm_f16 (unchanged from R6): m97-style global_load_lds staging, XOR swizzle,
// BK=64, 512 threads, MFMA 16x16x32_f16.
// ---------------------------------------------------------------------------
struct GArgs {
  const _Float16* A; const _Float16* Bt; const float* bias;
  void* out; int leaky, half_out;
};

template<int BN, int WR, int WC>
__global__ __launch_bounds__(512, 4) void gemm_f16(GArgs g0, GArgs g1, GArgs g2)
{
  const GArgs g = (blockIdx.z == 0) ? g0 : (blockIdx.z == 1) ? g1 : g2;
  constexpr int FM = 128 / WR / 16;
  constexpr int FN = BN / WC / 16;
  __shared__ _Float16 As[128 * 64];
  __shared__ _Float16 Bs[BN * 64];
  const int tid = threadIdx.x;
  const int m0 = blockIdx.y * 128, n0 = blockIdx.x * BN;
  const int lane = tid & 63, wave = tid >> 6;
  const int lm = lane & 15, qd = lane >> 4;
  const int wr = wave % WR, wc = wave / WR;
  const int wm0 = wr * (128 / WR), wn0 = wc * (BN / WC);
  const int srow = lane >> 3;
  const int sseg = (lane & 7) ^ srow;
  const _Float16* gA = g.A  + (size_t)(m0 + srow) * Dx + sseg * 8;
  const _Float16* gB = g.Bt + (size_t)(n0 + srow) * Dx + sseg * 8;

  f4 acc[FM][FN];
#pragma unroll
  for (int i = 0; i < FM; i++)
#pragma unroll
    for (int j = 0; j < FN; j++) { f4 z = {0.f, 0.f, 0.f, 0.f}; acc[i][j] = z; }

  for (int kt = 0; kt < Dx; kt += 64) {
    __syncthreads();
#pragma unroll
    for (int u = 0; u < 2; u++) {
      const int t = wave * 2 + u;
      gl2lds16(gA + (size_t)(t * 8) * Dx + kt, &As[t * 512]);
    }
#pragma unroll
    for (int u = 0; u < BN / 64; u++) {
      const int t = wave * (BN / 64) + u;
      gl2lds16(gB + (size_t)(t * 8) * Dx + kt, &Bs[t * 512]);
    }
    __syncthreads();
#pragma unroll
    for (int kk = 0; kk < 2; kk++) {
      const int sp = ((kk * 4 + qd) ^ (lm & 7)) * 8;
      h8 af[FM];
#pragma unroll
      for (int i = 0; i < FM; i++)
        af[i] = *(const h8*)&As[(wm0 + i * 16 + lm) * 64 + sp];
#pragma unroll
      for (int j = 0; j < FN; j++) {
        const h8 bf = *(const h8*)&Bs[(wn0 + j * 16 + lm) * 64 + sp];
#pragma unroll
        for (int i = 0; i < FM; i++)
          acc[i][j] = __builtin_amdgcn_mfma_f32_16x16x32_f16(af[i], bf, acc[i][j], 0, 0, 0);
      }
    }
  }

#pragma unroll
  for (int j = 0; j < FN; j++) {
    const int n = n0 + wn0 + j * 16 + lm;
    const float bz = g.bias[n];
#pragma unroll
    for (int i = 0; i < FM; i++) {
      const int mb = m0 + wm0 + i * 16 + qd * 4;
#pragma unroll
      for (int r = 0; r < 4; r++) {
        float v = acc[i][j][r] + bz;
        if (g.leaky) v = (v >= 0.f) ? v : 0.1f * v;
        if (g.half_out) ((_Float16*)g.out)[(size_t)(mb + r) * Dx + n] = (_Float16)v;
        else            ((float*)g.out)[(size_t)(mb + r) * Dx + n] = v;
      }
    }
  }
}

// ---------------------------------------------------------------------------
// chunkkv_mfma: S_c^T = V_c^T K_c  (64x64x64 MFMA), output fp16 [e][d];
// plus k-sums cz. 256 threads = 4 waves, wave = 16-row e-stripe.
// K,V staged TRANSPOSED ([d][s], [e][s]) with XOR-swizzled 16B segments.
// ---------------------------------------------------------------------------
__global__ __launch_bounds__(256) void chunkkv_mfma(
    const _Float16* __restrict__ kp, const _Float16* __restrict__ vp,
    _Float16* __restrict__ ckvh, float* __restrict__ cz)
{
  __shared__ _Float16 Kt[64 * 64];   // [d][s] swizzled
  __shared__ _Float16 Vt[64 * 64];   // [e][s] swizzled
  const int blk = blockIdx.x;
  const int c = blk & (NCx - 1);
  const int bh = blk / NCx;
  const int b = bh / Hx, h = bh % Hx;
  const int tid = threadIdx.x;
  const size_t rowbase = ((size_t)(b * Sx + c * 64)) * Dx + h * 64;

#pragma unroll
  for (int p = 0; p < 2; p++) {
    const int f = tid + 256 * p;
    const int s = f >> 3, g8 = f & 7;
    const h8 hk = *(const h8*)&kp[rowbase + (size_t)s * Dx + g8 * 8];
    const h8 hv = *(const h8*)&vp[rowbase + (size_t)s * Dx + g8 * 8];
#pragma unroll
    for (int i = 0; i < 8; i++) {
      const int r = g8 * 8 + i;       // d for Kt, e for Vt
      const int a = r * 64 + (((s >> 3) ^ (r & 7)) * 8) + (s & 7);
      Kt[a] = hk[i];
      Vt[a] = hv[i];
    }
  }
  __syncthreads();

  const int lane = tid & 63, w = tid >> 6;
  const int lm = lane & 15, qd = lane >> 4;
  const int x7 = lm & 7;

  h8 av[2];
#pragma unroll
  for (int kk = 0; kk < 2; kk++)
    av[kk] = *(const h8*)&Vt[(w * 16 + lm) * 64 + (((kk << 2) + qd) ^ x7) * 8];

#pragma unroll
  for (int dt = 0; dt < 4; dt++) {
    f4 acc = {0.f, 0.f, 0.f, 0.f};
#pragma unroll
    for (int kk = 0; kk < 2; kk++) {
      const h8 bf = *(const h8*)&Kt[(dt * 16 + lm) * 64 + (((kk << 2) + qd) ^ x7) * 8];
      acc = __builtin_amdgcn_mfma_f32_16x16x32_f16(av[kk], bf, acc, 0, 0, 0);
    }
#pragma unroll
    for (int r = 0; r < 4; r++) {
      const int e = w * 16 + qd * 4 + r;
      ckvh[(size_t)blk * 4096 + e * 64 + dt * 16 + lm] = (_Float16)acc[r];
    }
  }

  // cz[d] = sum_s K[s][d] = rowsum of Kt row d (order-independent: segs as-is)
  {
    const int d = tid >> 2, fr = tid & 3;
    float dp = 0.f;
#pragma unroll
    for (int j = 0; j < 2; j++) {
      const h8 kv = *(const h8*)&Kt[d * 64 + (fr * 2 + j) * 8];
#pragma unroll
      for (int i = 0; i < 8; i++) dp += (float)kv[i];
    }
    dp += __shfl_xor(dp, 1);
    dp += __shfl_xor(dp, 2);
    if (fr == 0) cz[(size_t)blk * 64 + d] = dp;
  }
}

// ---------------------------------------------------------------------------
// prefix: element-parallel exclusive scan over 32 chunks (fp16 data, fp32
// carry). 512 blocks x 256. z-scan stays fp32.
// ---------------------------------------------------------------------------
__global__ __launch_bounds__(256) void prefix_kernel(
    _Float16* __restrict__ ckvh, float* __restrict__ cz)
{
  const int gid = blockIdx.x * 256 + threadIdx.x;   // 0..131071
  const int bh = gid >> 12, el = gid & 4095;
  float acc = 0.f;
  for (int c = 0; c < NCx; c++) {
    const size_t idx = ((size_t)(bh * NCx + c) << 12) + el;
    const float v = (float)ckvh[idx];
    ckvh[idx] = (_Float16)acc;
    acc += v;
  }
  if (gid < BHx * 64) {
    const int zbh = gid >> 6, d = gid & 63;
    float az = 0.f;
    for (int c = 0; c < NCx; c++) {
      const size_t zi = (size_t)(zbh * NCx + c) * 64 + d;
      const float v = cz[zi];
      cz[zi] = az;
      az += v;
    }
  }
}

// ---------------------------------------------------------------------------
// attn_mfma: per chunk, P = tril(Q K^T) via MFMA; O = P@V + Q@S_excl via MFMA
// (accumulated in one C-reg set); den = q.z_excl (VALU) + rowsum(P) (shfl).
// 256 threads = 4 waves, wave = 16-row t-stripe. All LDS 64x64 fp16 rows with
// XOR-swizzled 16B segs (seg^row&7) -> frag reads 2-way max (free). Pa
// overlays Ks after phase 1. LDS = 32.5 KB -> 4 blocks/CU (grid resident).
// ---------------------------------------------------------------------------
__global__ __launch_bounds__(256) void attn_mfma(
    const _Float16* __restrict__ qp, const _Float16* __restrict__ kp,
    const _Float16* __restrict__ vp, const _Float16* __restrict__ ckvh,
    const float* __restrict__ cz, _Float16* __restrict__ concat)
{
  __shared__ _Float16 Qs[64 * 64];   // [t][d] swizzled
  __shared__ _Float16 Ks[64 * 64];   // [s][d] swizzled; reused as Pa [t][s]
  __shared__ _Float16 Vt[64 * 64];   // [e][s] swizzled
  __shared__ _Float16 Sh[64 * 64];   // [e][d] swizzled (S_excl^T fp16)
  __shared__ float zs[64];
  __shared__ float den[64];
  const int blk = blockIdx.x;
  const int c = blk & (NCx - 1);
  const int bh = blk / NCx;
  const int b = bh / Hx, h = bh % Hx;
  const int tid = threadIdx.x;
  const size_t rowbase = ((size_t)(b * Sx + c * 64)) * Dx + h * 64;

  // stage Q, K, Sh (row-major, swizzled segs)
#pragma unroll
  for (int p = 0; p < 2; p++) {
    const int f = tid + 256 * p;
    const int r = f >> 3, sg = f & 7;
    const int ph = (sg ^ (r & 7)) * 8;
    *(h8*)&Qs[r * 64 + ph] = *(const h8*)&qp[rowbase + (size_t)r * Dx + sg * 8];
    *(h8*)&Ks[r * 64 + ph] = *(const h8*)&kp[rowbase + (size_t)r * Dx + sg * 8];
    *(h8*)&Sh[r * 64 + ph] = *(const h8*)&ckvh[(size_t)blk * 4096 + r * 64 + sg * 8];
  }
  // stage V transposed [e][s]
#pragma unroll
  for (int p = 0; p < 2; p++) {
    const int f = tid + 256 * p;
    const int s = f >> 3, g8 = f & 7;
    const h8 hv = *(const h8*)&vp[rowbase + (size_t)s * Dx + g8 * 8];
#pragma unroll
    for (int i = 0; i < 8; i++) {
      const int e = g8 * 8 + i;
      Vt[e * 64 + (((s >> 3) ^ (e & 7)) * 8) + (s & 7)] = hv[i];
    }
  }
  if (tid < 64) zs[tid] = cz[(size_t)blk * 64 + tid];
  __syncthreads();

  const int lane = tid & 63, w = tid >> 6;
  const int lm = lane & 15, qd = lane >> 4;
  const int x7 = lm & 7;

  // A-frags for this wave's Q stripe (reused in phases 1 and 3)
  h8 aq[2];
#pragma unroll
  for (int kk = 0; kk < 2; kk++)
    aq[kk] = *(const h8*)&Qs[(w * 16 + lm) * 64 + (((kk << 2) + qd) ^ x7) * 8];

  // phase 1: P = Q K^T, 4 s-tiles
  f4 pc[4];
#pragma unroll
  for (int st = 0; st < 4; st++) {
    f4 z4 = {0.f, 0.f, 0.f, 0.f}; pc[st] = z4;
#pragma unroll
    for (int kk = 0; kk < 2; kk++) {
      const h8 bf = *(const h8*)&Ks[(st * 16 + lm) * 64 + (((kk << 2) + qd) ^ x7) * 8];
      pc[st] = __builtin_amdgcn_mfma_f32_16x16x32_f16(aq[kk], bf, pc[st], 0, 0, 0);
    }
  }
  // causal mask + rowsums
  float rsum[4] = {0.f, 0.f, 0.f, 0.f};
#pragma unroll
  for (int st = 0; st < 4; st++) {
    const int s = st * 16 + lm;
#pragma unroll
    for (int r = 0; r < 4; r++) {
      const int t = w * 16 + qd * 4 + r;
      float v = pc[st][r];
      v = (s <= t) ? v : 0.f;
      pc[st][r] = v;
      rsum[r] += v;
    }
  }
#pragma unroll
  for (int r = 0; r < 4; r++) {
    rsum[r] += __shfl_xor(rsum[r], 1);
    rsum[r] += __shfl_xor(rsum[r], 2);
    rsum[r] += __shfl_xor(rsum[r], 4);
    rsum[r] += __shfl_xor(rsum[r], 8);
  }
  // den[t] = q . z_excl  (t = tid>>2, quarter-dot + shfl)
  {
    const int t = tid >> 2, fr = tid & 3;
    float dp = 0.f;
#pragma unroll
    for (int j = 0; j < 2; j++) {
      const int sg = fr * 2 + j;
      const h8 qv = *(const h8*)&Qs[t * 64 + (sg ^ (t & 7)) * 8];
#pragma unroll
      for (int i = 0; i < 8; i++) dp += (float)qv[i] * zs[sg * 8 + i];
    }
    dp += __shfl_xor(dp, 1);
    dp += __shfl_xor(dp, 2);
    if (fr == 0) den[t] = dp;
  }
  __syncthreads();           // Ks reads done; den[t] written

  // write Pa (fp16, A-layout, swizzled) over Ks; fold rowsums into den
  _Float16* Pa = Ks;
#pragma unroll
  for (int st = 0; st < 4; st++) {
#pragma unroll
    for (int r = 0; r < 4; r++) {
      const int row = w * 16 + qd * 4 + r;
      Pa[row * 64 + (((st * 2 + (lm >> 3)) ^ (row & 7)) * 8) + (lm & 7)] =
          (_Float16)pc[st][r];
    }
  }
  if (lm == 0) {
#pragma unroll
    for (int r = 0; r < 4; r++) den[w * 16 + qd * 4 + r] += rsum[r];
  }
  __syncthreads();

  // phases 2+3: O = P@V + Q@S_excl  (same accumulators)
  h8 ap[2];
#pragma unroll
  for (int kk = 0; kk < 2; kk++)
    ap[kk] = *(const h8*)&Pa[(w * 16 + lm) * 64 + (((kk << 2) + qd) ^ x7) * 8];

  f4 acc[4];
#pragma unroll
  for (int et = 0; et < 4; et++) {
    f4 z4 = {0.f, 0.f, 0.f, 0.f}; acc[et] = z4;
#pragma unroll
    for (int kk = 0; kk < 2; kk++) {
      const h8 bv = *(const h8*)&Vt[(et * 16 + lm) * 64 + (((kk << 2) + qd) ^ x7) * 8];
      acc[et] = __builtin_amdgcn_mfma_f32_16x16x32_f16(ap[kk], bv, acc[et], 0, 0, 0);
    }
#pragma unroll
    for (int kk = 0; kk < 2; kk++) {
      const h8 bs = *(const h8*)&Sh[(et * 16 + lm) * 64 + (((kk << 2) + qd) ^ x7) * 8];
      acc[et] = __builtin_amdgcn_mfma_f32_16x16x32_f16(aq[kk], bs, acc[et], 0, 0, 0);
    }
  }

  // epilogue: divide by den, write fp16 concat
#pragma unroll
  for (int r = 0; r < 4; r++) {
    const int row = w * 16 + qd * 4 + r;
    const float inv = 1.f / den[row];
    _Float16* orow = &concat[((size_t)(b * Sx + c * 64 + row)) * Dx + h * 64];
#pragma unroll
    for (int et = 0; et < 4; et++)
      orow[et * 16 + lm] = (_Float16)(acc[et][r] * inv);
  }
}

// ---------------------------------------------------------------------------
extern "C" void kernel_launch(void* const* d_in, const int* in_sizes, int n_in,
                              void* d_out, int out_size, void* d_ws, size_t ws_size,
                              hipStream_t stream)
{
  const float* q  = (const float*)d_in[0];
  const float* k  = (const float*)d_in[1];
  const float* v  = (const float*)d_in[2];
  const float* qm = (const float*)d_in[3];
  const float* km = (const float*)d_in[4];
  const float* vm = (const float*)d_in[5];
  const float* Wq = (const float*)d_in[6];
  const float* bq = (const float*)d_in[7];
  const float* Wk = (const float*)d_in[8];
  const float* bk = (const float*)d_in[9];
  const float* Wv = (const float*)d_in[10];
  const float* bv = (const float*)d_in[11];
  const float* Wo = (const float*)d_in[12];
  const float* bo = (const float*)d_in[13];
  float* out = (float*)d_out;

  // workspace layout (bytes), total 56.25 MB (same footprint as proven R6).
  char* ws = (char*)d_ws;
  _Float16* qh  = (_Float16*)(ws);                 //  8 MB
  _Float16* kh  = (_Float16*)(ws + 8388608);       //  8 MB
  _Float16* vh  = (_Float16*)(ws + 16777216);      //  8 MB
  _Float16* Wtq = (_Float16*)(ws + 25165824);      //  2 MB each
  _Float16* Wtk = (_Float16*)(ws + 27262976);
  _Float16* Wtv = (_Float16*)(ws + 29360128);
  _Float16* Wto = (_Float16*)(ws + 31457280);
  _Float16* qp  = (_Float16*)(ws + 33554432);      //  8 MB
  _Float16* kp  = (_Float16*)(ws + 41943040);      //  8 MB
  _Float16* vp  = (_Float16*)(ws + 50331648);      //  8 MB
  float*    cz  = (float*)   (ws + 58720256);      //  256 KB
  _Float16* ckvh   = qh;                           //  8 MB over dead qh
  _Float16* concat = kh;                           //  8 MB over dead kh

  convert_in<<<dim3(4096, 3), 256, 0, stream>>>(q, k, v, qm, km, vm, qh, kh, vh);
  convert_w<<<dim3(16, 16, 4), 256, 0, stream>>>(Wq, Wk, Wv, Wo, Wtq, Wtk, Wtv, Wto);

  GArgs gq = { qh, Wtq, bq, qp, 1, 1 };
  GArgs gk = { kh, Wtk, bk, kp, 1, 1 };
  GArgs gv = { vh, Wtv, bv, vp, 0, 1 };
  gemm_f16<256, 2, 4><<<dim3(Dx / 256, Mx / 128, 3), 512, 0, stream>>>(gq, gk, gv);

  chunkkv_mfma<<<BHx * NCx, 256, 0, stream>>>(kp, vp, ckvh, cz);
  prefix_kernel<<<512, 256, 0, stream>>>(ckvh, cz);
  attn_mfma<<<BHx * NCx, 256, 0, stream>>>(qp, kp, vp, ckvh, cz, concat);

  GArgs go = { concat, Wto, bo, out, 0, 0 };
  gemm_f16<128, 4, 2><<<dim3(Dx / 128, Mx / 128, 1), 512, 0, stream>>>(go, go, go);
}